// Round 2
// baseline (982.042 us; speedup 1.0000x reference)
//
#include <hip/hip_runtime.h>
#include <hip/hip_bf16.h>
#include <math.h>

#define NND 50000
#define NE 800000
#define NF 128
#define NH 64
#define NB 512
#define KP 30
#define NCLS 10

typedef __hip_bfloat16 bf16;

// runtime dtype-adaptive loads (flags probed on device)
__device__ __forceinline__ float ldF(const void* p, size_t i, int isbf){
    return isbf ? __bfloat162float(((const bf16*)p)[i]) : ((const float*)p)[i];
}

// ---------------- dtype probe: flags[0]=floats-are-bf16, flags[1]=ints-are-int64 ----
__global__ void probe_kernel(const unsigned int* __restrict__ xw,
                             const int* __restrict__ ew, int* __restrict__ flags){
    __shared__ int cF, cI;
    if (threadIdx.x == 0){ cF = 0; cI = 0; }
    __syncthreads();
    // low 16 bits of word i viewed as bf16: real bf16 data has sane exponent;
    // fp32 data has uniform mantissa bits there.
    unsigned int w = xw[threadIdx.x];
    int ex = (int)((w >> 7) & 0xFF);
    if (ex >= 100 && ex <= 140) atomicAdd(&cF, 1);
    // little-endian int64 => every odd int32 word of edge_index is 0
    if (ew[2*threadIdx.x + 1] == 0) atomicAdd(&cI, 1);
    __syncthreads();
    if (threadIdx.x == 0){
        flags[0] = (cF >= 128) ? 1 : 0;
        flags[1] = (cI >= 192) ? 1 : 0;
    }
}

// ---------------- degree (edge count per dst) ----------------
__global__ __launch_bounds__(256) void deg_kernel(const int* __restrict__ ei,
                                                  float* __restrict__ deg,
                                                  const int* __restrict__ flags){
    int e = blockIdx.x*256 + threadIdx.x;
    if (e >= NE) return;
    int i64 = flags[1];
    int d = i64 ? ei[2*NE + 2*e] : ei[NE + e];
    atomicAdd(&deg[d], 1.0f);
}

// ---------------- per-graph start offsets (batch sorted) ----------------
__global__ __launch_bounds__(256) void starts_kernel(const int* __restrict__ batch,
                                                     int* __restrict__ starts,
                                                     const int* __restrict__ flags){
    int i = blockIdx.x*256 + threadIdx.x;
    if (i >= NND) return;
    int i64 = flags[1];
    int b  = i64 ? batch[2*i] : batch[i];
    int pb = (i == 0) ? -1 : (i64 ? batch[2*(i-1)] : batch[i-1]);
    for (int g = pb+1; g <= b; ++g) starts[g] = i;
    if (i == NND-1) for (int g = b+1; g <= NB; ++g) starts[g] = NND;
}

// ---------------- GEMM: out[n,64] = in[n,K] @ W[K,64]  (+ optional SAGE finalize) ----
template<int K, bool FIN>
__global__ __launch_bounds__(256) void sage_gemm(
    const void* __restrict__ in, const void* __restrict__ W,
    const void* __restrict__ bias, const float* __restrict__ agg,
    const float* __restrict__ deg, float* __restrict__ out,
    const int* __restrict__ flags, int inIsF32)
{
    __shared__ float Wl[K*NH];
    __shared__ float inR[16*K];
    int isbf = inIsF32 ? 0 : flags[0];
    int wbf  = flags[0];
    int tid = threadIdx.x;
    for (int i = tid; i < K*NH; i += 256) Wl[i] = ldF(W, i, wbf);
    int base = blockIdx.x * 16;
    for (int i = tid; i < 16*K; i += 256){
        int r = i / K, c = i - r*K;
        int node = base + r;
        inR[i] = (node < NND) ? ldF(in, (size_t)node*K + c, isbf) : 0.f;
    }
    __syncthreads();
    int f = tid & 63, ng = tid >> 6;
    float acc0=0.f, acc1=0.f, acc2=0.f, acc3=0.f;
    const float* r0 = &inR[(ng*4+0)*K];
    const float* r1 = &inR[(ng*4+1)*K];
    const float* r2 = &inR[(ng*4+2)*K];
    const float* r3 = &inR[(ng*4+3)*K];
    #pragma unroll 8
    for (int k = 0; k < K; ++k){
        float w = Wl[k*NH + f];
        acc0 += w*r0[k]; acc1 += w*r1[k]; acc2 += w*r2[k]; acc3 += w*r3[k];
    }
    float bv = FIN ? ldF(bias, f, wbf) : 0.f;
    float accs[4] = {acc0,acc1,acc2,acc3};
    #pragma unroll
    for (int j = 0; j < 4; ++j){
        int node = base + ng*4 + j;
        if (node < NND){
            float v = accs[j];
            if (FIN){
                float d = deg[node]; d = d > 1.f ? d : 1.f;
                v = agg[(size_t)node*NH+f]/d + bv + v;
                v = v > 0.f ? v : 0.f;   // relu
            }
            out[(size_t)node*NH+f] = v;
        }
    }
}

// ---------------- edge scatter: agg[dst] += y[src], 64 feats/edge ----------------
__global__ __launch_bounds__(256) void scatter_kernel(
    const float* __restrict__ y, const int* __restrict__ ei,
    float* __restrict__ agg, const int* __restrict__ flags)
{
    long long idx = (long long)blockIdx.x*256 + threadIdx.x;
    if (idx >= (long long)NE*64) return;
    int e = (int)(idx >> 6);
    int f = (int)(idx & 63);
    int i64 = flags[1];
    int s = i64 ? ei[2*e]        : ei[e];
    int d = i64 ? ei[2*NE + 2*e] : ei[NE + e];
    atomicAdd(&agg[(size_t)d*NH + f], y[(size_t)s*NH + f]);
}

// ---------------- fused head: sort-pool topK + conv1d + fc1 + fc2 + log_softmax ----
__global__ __launch_bounds__(256) void head_kernel(
    const float* __restrict__ h3, const int* __restrict__ starts,
    const void* __restrict__ convw, const void* __restrict__ convb,
    const void* __restrict__ lin1w, const void* __restrict__ lin1b,
    const void* __restrict__ lin2w, const void* __restrict__ lin2b,
    float* __restrict__ outp, const int* __restrict__ flags)
{
    __shared__ float vals[2048];
    __shared__ float pooled[KP][NH+1];   // +1 pad kills 64-stride bank conflicts
    __shared__ float cw[32*NH*5];
    __shared__ float cbuf[32*26];
    __shared__ float part[4][NH];
    __shared__ float fbuf[NH];
    __shared__ float rv[256];
    __shared__ int   ri[256];
    __shared__ int   sel[KP];
    __shared__ float logitsS[NCLS];

    int wbf = flags[0];
    int g = blockIdx.x, tid = threadIdx.x;
    int s = starts[g], e = starts[g+1];
    int cnt = e - s; if (cnt > 2048) cnt = 2048; if (cnt < 0) cnt = 0;

    for (int i = tid; i < cnt; i += 256) vals[i] = h3[(size_t)(s+i)*NH + 63];
    for (int i = tid; i < 32*NH*5; i += 256) cw[i] = ldF(convw, i, wbf);
    __syncthreads();

    // top-K: value desc, tie -> smaller index (matches stable lexsort)
    for (int r = 0; r < KP; ++r){
        float bv = -1e30f; int bi = 0x7fffffff;
        for (int i = tid; i < cnt; i += 256){
            float v = vals[i];
            if (v > bv || (v == bv && i < bi)){ bv = v; bi = i; }
        }
        rv[tid] = bv; ri[tid] = bi;
        __syncthreads();
        for (int st = 128; st > 0; st >>= 1){
            if (tid < st){
                float ov = rv[tid+st]; int oi = ri[tid+st];
                if (ov > rv[tid] || (ov == rv[tid] && oi < ri[tid])){ rv[tid]=ov; ri[tid]=oi; }
            }
            __syncthreads();
        }
        if (tid == 0){
            if (rv[0] > -1e29f){ sel[r] = ri[0]; vals[ri[0]] = -1e30f; }
            else sel[r] = -1;
        }
        __syncthreads();
    }

    for (int i = tid; i < KP*NH; i += 256){
        int r = i >> 6, f = i & 63;
        int li = sel[r];
        pooled[r][f] = (li >= 0) ? h3[(size_t)(s+li)*NH + f] : 0.f;
    }
    __syncthreads();

    // conv1d over rank axis
    for (int i = tid; i < 32*26; i += 256){
        int o = i / 26, t = i - o*26;
        float a = ldF(convb, o, wbf);
        const float* wo = &cw[o*NH*5];
        for (int ch = 0; ch < NH; ++ch){
            #pragma unroll
            for (int h = 0; h < 5; ++h)
                a += pooled[t+h][ch] * wo[ch*5+h];
        }
        cbuf[o*26+t] = a > 0.f ? a : 0.f;
    }
    __syncthreads();

    // fc1 (832 -> 64)
    {
        int p = tid >> 6, j = tid & 63;
        float a = 0.f;
        int m0 = p*208, m1 = m0+208;
        for (int m = m0; m < m1; ++m)
            a += cbuf[m] * ldF(lin1w, (size_t)m*NH + j, wbf);
        part[p][j] = a;
    }
    __syncthreads();
    if (tid < NH){
        float v = part[0][tid]+part[1][tid]+part[2][tid]+part[3][tid] + ldF(lin1b, tid, wbf);
        fbuf[tid] = v > 0.f ? v : 0.f;
    }
    __syncthreads();

    // fc2 + log_softmax
    if (tid < NCLS){
        float a = ldF(lin2b, tid, wbf);
        for (int j = 0; j < NH; ++j) a += fbuf[j] * ldF(lin2w, (size_t)j*NCLS + tid, wbf);
        logitsS[tid] = a;
    }
    __syncthreads();
    if (tid == 0){
        float m = logitsS[0];
        for (int c = 1; c < NCLS; ++c) m = fmaxf(m, logitsS[c]);
        float ssum = 0.f;
        for (int c = 0; c < NCLS; ++c) ssum += expf(logitsS[c]-m);
        float lse = m + logf(ssum);
        for (int c = 0; c < NCLS; ++c)
            outp[(size_t)g*NCLS + c] = logitsS[c] - lse;
    }
}

extern "C" void kernel_launch(void* const* d_in, const int* in_sizes, int n_in,
                              void* d_out, int out_size, void* d_ws, size_t ws_size,
                              hipStream_t stream) {
    const void* x    = d_in[0];
    const int*  ei   = (const int*)d_in[1];
    const int*  batch= (const int*)d_in[2];
    const void *W1l=d_in[3], *b1=d_in[4],  *W1r=d_in[5];
    const void *W2l=d_in[6], *b2=d_in[7],  *W2r=d_in[8];
    const void *W3l=d_in[9], *b3=d_in[10], *W3r=d_in[11];
    const void *convw=d_in[12], *convb=d_in[13];
    const void *l1w=d_in[14], *l1b=d_in[15];
    const void *l2w=d_in[16], *l2b=d_in[17];
    float* out = (float*)d_out;

    float* wsf = (float*)d_ws;
    float* y    = wsf;                          // 50000*64
    float* agg  = y   + (size_t)NND*NH;         // 50000*64
    float* hA   = agg + (size_t)NND*NH;         // 50000*64
    float* hB   = hA  + (size_t)NND*NH;         // 50000*64
    float* deg  = hB  + (size_t)NND*NH;         // 50000
    int* starts = (int*)(deg + NND);            // 513
    int* flags  = starts + 520;                 // 2

    probe_kernel<<<1, 256, 0, stream>>>((const unsigned int*)x, ei, flags);

    hipMemsetAsync(deg, 0, NND*sizeof(float), stream);
    deg_kernel<<<(NE+255)/256, 256, 0, stream>>>(ei, deg, flags);
    starts_kernel<<<(NND+255)/256, 256, 0, stream>>>(batch, starts, flags);

    int gblocks = (NND + 15)/16;
    long long nTh = (long long)NE*64;
    int sblocks = (int)((nTh + 255)/256);
    size_t aggBytes = (size_t)NND*NH*sizeof(float);

    // ---- layer 1 (input x, K=128) ----
    hipMemsetAsync(agg, 0, aggBytes, stream);
    sage_gemm<NF,false><<<gblocks,256,0,stream>>>(x, W1l, nullptr, nullptr, nullptr, y, flags, 0);
    scatter_kernel<<<sblocks,256,0,stream>>>(y, ei, agg, flags);
    sage_gemm<NF,true ><<<gblocks,256,0,stream>>>(x, W1r, b1, agg, deg, hA, flags, 0);

    // ---- layer 2 (input hA: f32 ws, K=64) ----
    hipMemsetAsync(agg, 0, aggBytes, stream);
    sage_gemm<NH,false><<<gblocks,256,0,stream>>>(hA, W2l, nullptr, nullptr, nullptr, y, flags, 1);
    scatter_kernel<<<sblocks,256,0,stream>>>(y, ei, agg, flags);
    sage_gemm<NH,true ><<<gblocks,256,0,stream>>>(hA, W2r, b2, agg, deg, hB, flags, 1);

    // ---- layer 3 (input hB: f32 ws, K=64) ----
    hipMemsetAsync(agg, 0, aggBytes, stream);
    sage_gemm<NH,false><<<gblocks,256,0,stream>>>(hB, W3l, nullptr, nullptr, nullptr, y, flags, 1);
    scatter_kernel<<<sblocks,256,0,stream>>>(y, ei, agg, flags);
    sage_gemm<NH,true ><<<gblocks,256,0,stream>>>(hB, W3r, b3, agg, deg, hA, flags, 1);

    // ---- head ----
    head_kernel<<<NB,256,0,stream>>>(hA, starts, convw, convb, l1w, l1b, l2w, l2b, out, flags);
}

// Round 3
// 691.327 us; speedup vs baseline: 1.4205x; 1.4205x over previous
//
#include <hip/hip_runtime.h>
#include <hip/hip_bf16.h>
#include <math.h>

#define NND 50000
#define NE 800000
#define NF 128
#define NH 64
#define NB 512
#define KP 30
#define NCLS 10

typedef __hip_bfloat16 bf16;

// runtime dtype-adaptive loads (flags probed on device)
__device__ __forceinline__ float ldF(const void* p, size_t i, int isbf){
    return isbf ? __bfloat162float(((const bf16*)p)[i]) : ((const float*)p)[i];
}

// ---------------- dtype probe: flags[0]=floats-are-bf16, flags[1]=ints-are-int64 ----
__global__ void probe_kernel(const unsigned int* __restrict__ xw,
                             const int* __restrict__ ew, int* __restrict__ flags){
    __shared__ int cF, cI;
    if (threadIdx.x == 0){ cF = 0; cI = 0; }
    __syncthreads();
    unsigned int w = xw[threadIdx.x];
    int ex = (int)((w >> 7) & 0xFF);
    if (ex >= 100 && ex <= 140) atomicAdd(&cF, 1);
    if (ew[2*threadIdx.x + 1] == 0) atomicAdd(&cI, 1);
    __syncthreads();
    if (threadIdx.x == 0){
        flags[0] = (cF >= 128) ? 1 : 0;
        flags[1] = (cI >= 192) ? 1 : 0;
    }
}

__device__ __forceinline__ int edgeSrc(const int* ei, int e, int i64){
    return i64 ? ei[2*e] : ei[e];
}
__device__ __forceinline__ int edgeDst(const int* ei, int e, int i64){
    return i64 ? ei[2*NE + 2*e] : ei[NE + e];
}

// ---------------- per-graph start offsets (batch sorted) ----------------
__global__ __launch_bounds__(256) void starts_kernel(const int* __restrict__ batch,
                                                     int* __restrict__ starts,
                                                     const int* __restrict__ flags){
    int i = blockIdx.x*256 + threadIdx.x;
    if (i >= NND) return;
    int i64 = flags[1];
    int b  = i64 ? batch[2*i] : batch[i];
    int pb = (i == 0) ? -1 : (i64 ? batch[2*(i-1)] : batch[i-1]);
    for (int g = pb+1; g <= b; ++g) starts[g] = i;
    if (i == NND-1) for (int g = b+1; g <= NB; ++g) starts[g] = NND;
}

// ---------------- CSR build ----------------
__global__ __launch_bounds__(256) void count_kernel(const int* __restrict__ ei,
                                                    int* __restrict__ cnt,
                                                    const int* __restrict__ flags){
    int e = blockIdx.x*256 + threadIdx.x;
    if (e >= NE) return;
    atomicAdd(&cnt[edgeDst(ei, e, flags[1])], 1);
}

__global__ __launch_bounds__(1024) void scan_kernel(const int* __restrict__ cnt,
                                                    int* __restrict__ offs){
    __shared__ int buf[1024];
    __shared__ int runS;
    int tid = threadIdx.x;
    if (tid == 0) runS = 0;
    __syncthreads();
    for (int base = 0; base < NND; base += 1024){
        int i = base + tid;
        int v = (i < NND) ? cnt[i] : 0;
        buf[tid] = v;
        __syncthreads();
        for (int st = 1; st < 1024; st <<= 1){
            int t = (tid >= st) ? buf[tid-st] : 0;
            __syncthreads();
            buf[tid] += t;
            __syncthreads();
        }
        if (i < NND) offs[i] = runS + buf[tid] - v;
        int tot = buf[1023];
        __syncthreads();
        if (tid == 0) runS += tot;
        __syncthreads();
    }
    if (tid == 0) offs[NND] = runS;
}

__global__ __launch_bounds__(256) void fill_kernel(const int* __restrict__ ei,
                                                   const int* __restrict__ offs,
                                                   int* __restrict__ cur,
                                                   int* __restrict__ csr,
                                                   const int* __restrict__ flags){
    int e = blockIdx.x*256 + threadIdx.x;
    if (e >= NE) return;
    int i64 = flags[1];
    int d = edgeDst(ei, e, i64);
    int p = atomicAdd(&cur[d], 1);
    csr[offs[d] + p] = edgeSrc(ei, e, i64);
}

// ---------------- GEMM: y[n,64] = in[n,K] @ W[K,64] ----------------
template<int K>
__global__ __launch_bounds__(256) void gemm_l(
    const void* __restrict__ in, const void* __restrict__ W,
    float* __restrict__ out, const int* __restrict__ flags, int inIsF32)
{
    __shared__ float Wl[K*NH];
    __shared__ float inR[16*K];
    int isbf = inIsF32 ? 0 : flags[0];
    int wbf  = flags[0];
    int tid = threadIdx.x;
    for (int i = tid; i < K*NH; i += 256) Wl[i] = ldF(W, i, wbf);
    int base = blockIdx.x * 16;
    for (int i = tid; i < 16*K; i += 256){
        int r = i / K, c = i - r*K;
        int node = base + r;
        inR[i] = (node < NND) ? ldF(in, (size_t)node*K + c, isbf) : 0.f;
    }
    __syncthreads();
    int f = tid & 63, ng = tid >> 6;
    float acc0=0.f, acc1=0.f, acc2=0.f, acc3=0.f;
    const float* r0 = &inR[(ng*4+0)*K];
    const float* r1 = &inR[(ng*4+1)*K];
    const float* r2 = &inR[(ng*4+2)*K];
    const float* r3 = &inR[(ng*4+3)*K];
    #pragma unroll 8
    for (int k = 0; k < K; ++k){
        float w = Wl[k*NH + f];
        acc0 += w*r0[k]; acc1 += w*r1[k]; acc2 += w*r2[k]; acc3 += w*r3[k];
    }
    float accs[4] = {acc0,acc1,acc2,acc3};
    #pragma unroll
    for (int j = 0; j < 4; ++j){
        int node = base + ng*4 + j;
        if (node < NND) out[(size_t)node*NH+f] = accs[j];
    }
}

// ---- fused finalize: h' = relu( csr_mean(y) + b + h@Wr ) ----
template<int K>
__global__ __launch_bounds__(256) void finalize_kernel(
    const void* __restrict__ in, const void* __restrict__ Wr,
    const void* __restrict__ bias, const float* __restrict__ y,
    const int* __restrict__ offs, const int* __restrict__ csr,
    float* __restrict__ out, const int* __restrict__ flags, int inIsF32)
{
    __shared__ float Wl[K*NH];
    __shared__ float inR[16*K];
    int isbf = inIsF32 ? 0 : flags[0];
    int wbf  = flags[0];
    int tid = threadIdx.x;
    for (int i = tid; i < K*NH; i += 256) Wl[i] = ldF(Wr, i, wbf);
    int base = blockIdx.x * 16;
    for (int i = tid; i < 16*K; i += 256){
        int r = i / K, c = i - r*K;
        int node = base + r;
        inR[i] = (node < NND) ? ldF(in, (size_t)node*K + c, isbf) : 0.f;
    }
    __syncthreads();
    int f = tid & 63, ng = tid >> 6;
    float acc0=0.f, acc1=0.f, acc2=0.f, acc3=0.f;
    const float* r0 = &inR[(ng*4+0)*K];
    const float* r1 = &inR[(ng*4+1)*K];
    const float* r2 = &inR[(ng*4+2)*K];
    const float* r3 = &inR[(ng*4+3)*K];
    #pragma unroll 8
    for (int k = 0; k < K; ++k){
        float w = Wl[k*NH + f];
        acc0 += w*r0[k]; acc1 += w*r1[k]; acc2 += w*r2[k]; acc3 += w*r3[k];
    }
    float bv = ldF(bias, f, wbf);
    float accs[4] = {acc0,acc1,acc2,acc3};
    #pragma unroll
    for (int j = 0; j < 4; ++j){
        int node = base + ng*4 + j;
        if (node < NND){
            int o0 = offs[node], o1 = offs[node+1];
            float sacc = 0.f;
            int t = o0;
            for (; t + 3 < o1; t += 4){
                int i0 = csr[t], i1 = csr[t+1], i2 = csr[t+2], i3 = csr[t+3];
                sacc += y[(size_t)i0*NH+f] + y[(size_t)i1*NH+f]
                      + y[(size_t)i2*NH+f] + y[(size_t)i3*NH+f];
            }
            for (; t < o1; ++t) sacc += y[(size_t)csr[t]*NH+f];
            float dd = (float)(o1 - o0); dd = dd > 1.f ? dd : 1.f;
            float v = sacc/dd + bv + accs[j];
            out[(size_t)node*NH+f] = v > 0.f ? v : 0.f;
        }
    }
}

// ---------------- fused head: sort-pool topK + conv1d + fc1 + fc2 + log_softmax ----
__global__ __launch_bounds__(256) void head_kernel(
    const float* __restrict__ h3, const int* __restrict__ starts,
    const void* __restrict__ convw, const void* __restrict__ convb,
    const void* __restrict__ lin1w, const void* __restrict__ lin1b,
    const void* __restrict__ lin2w, const void* __restrict__ lin2b,
    float* __restrict__ outp, const int* __restrict__ flags)
{
    __shared__ float vals[2048];
    __shared__ float pooled[KP][NH+1];
    __shared__ float cw[32*NH*5];
    __shared__ float cbuf[32*26];
    __shared__ float part[4][NH];
    __shared__ float fbuf[NH];
    __shared__ float rv[256];
    __shared__ int   ri[256];
    __shared__ int   sel[KP];
    __shared__ float logitsS[NCLS];

    int wbf = flags[0];
    int g = blockIdx.x, tid = threadIdx.x;
    int s = starts[g], e = starts[g+1];
    int cnt = e - s; if (cnt > 2048) cnt = 2048; if (cnt < 0) cnt = 0;

    for (int i = tid; i < cnt; i += 256) vals[i] = h3[(size_t)(s+i)*NH + 63];
    for (int i = tid; i < 32*NH*5; i += 256) cw[i] = ldF(convw, i, wbf);
    __syncthreads();

    for (int r = 0; r < KP; ++r){
        float bv = -1e30f; int bi = 0x7fffffff;
        for (int i = tid; i < cnt; i += 256){
            float v = vals[i];
            if (v > bv || (v == bv && i < bi)){ bv = v; bi = i; }
        }
        rv[tid] = bv; ri[tid] = bi;
        __syncthreads();
        for (int st = 128; st > 0; st >>= 1){
            if (tid < st){
                float ov = rv[tid+st]; int oi = ri[tid+st];
                if (ov > rv[tid] || (ov == rv[tid] && oi < ri[tid])){ rv[tid]=ov; ri[tid]=oi; }
            }
            __syncthreads();
        }
        if (tid == 0){
            if (rv[0] > -1e29f){ sel[r] = ri[0]; vals[ri[0]] = -1e30f; }
            else sel[r] = -1;
        }
        __syncthreads();
    }

    for (int i = tid; i < KP*NH; i += 256){
        int r = i >> 6, f = i & 63;
        int li = sel[r];
        pooled[r][f] = (li >= 0) ? h3[(size_t)(s+li)*NH + f] : 0.f;
    }
    __syncthreads();

    for (int i = tid; i < 32*26; i += 256){
        int o = i / 26, t = i - o*26;
        float a = ldF(convb, o, wbf);
        const float* wo = &cw[o*NH*5];
        for (int ch = 0; ch < NH; ++ch){
            #pragma unroll
            for (int h = 0; h < 5; ++h)
                a += pooled[t+h][ch] * wo[ch*5+h];
        }
        cbuf[o*26+t] = a > 0.f ? a : 0.f;
    }
    __syncthreads();

    {
        int p = tid >> 6, j = tid & 63;
        float a = 0.f;
        int m0 = p*208, m1 = m0+208;
        for (int m = m0; m < m1; ++m)
            a += cbuf[m] * ldF(lin1w, (size_t)m*NH + j, wbf);
        part[p][j] = a;
    }
    __syncthreads();
    if (tid < NH){
        float v = part[0][tid]+part[1][tid]+part[2][tid]+part[3][tid] + ldF(lin1b, tid, wbf);
        fbuf[tid] = v > 0.f ? v : 0.f;
    }
    __syncthreads();

    if (tid < NCLS){
        float a = ldF(lin2b, tid, wbf);
        for (int j = 0; j < NH; ++j) a += fbuf[j] * ldF(lin2w, (size_t)j*NCLS + tid, wbf);
        logitsS[tid] = a;
    }
    __syncthreads();
    if (tid == 0){
        float m = logitsS[0];
        for (int c = 1; c < NCLS; ++c) m = fmaxf(m, logitsS[c]);
        float ssum = 0.f;
        for (int c = 0; c < NCLS; ++c) ssum += expf(logitsS[c]-m);
        float lse = m + logf(ssum);
        for (int c = 0; c < NCLS; ++c)
            outp[(size_t)g*NCLS + c] = logitsS[c] - lse;
    }
}

extern "C" void kernel_launch(void* const* d_in, const int* in_sizes, int n_in,
                              void* d_out, int out_size, void* d_ws, size_t ws_size,
                              hipStream_t stream) {
    const void* x    = d_in[0];
    const int*  ei   = (const int*)d_in[1];
    const int*  batch= (const int*)d_in[2];
    const void *W1l=d_in[3], *b1=d_in[4],  *W1r=d_in[5];
    const void *W2l=d_in[6], *b2=d_in[7],  *W2r=d_in[8];
    const void *W3l=d_in[9], *b3=d_in[10], *W3r=d_in[11];
    const void *convw=d_in[12], *convb=d_in[13];
    const void *l1w=d_in[14], *l1b=d_in[15];
    const void *l2w=d_in[16], *l2b=d_in[17];
    float* out = (float*)d_out;

    float* wsf = (float*)d_ws;
    float* y    = wsf;                          // 50000*64 f
    float* hA   = y   + (size_t)NND*NH;         // 50000*64 f
    float* hB   = hA  + (size_t)NND*NH;         // 50000*64 f
    int* starts = (int*)(hB + (size_t)NND*NH);  // 513
    int* flags  = starts + 520;                 // 2
    int* cnt    = flags + 8;                    // 50000
    int* offs   = cnt + NND;                    // 50001
    int* cur    = offs + NND + 4;               // 50000
    int* csr    = cur + NND;                    // 800000

    probe_kernel<<<1, 256, 0, stream>>>((const unsigned int*)x, ei, flags);
    starts_kernel<<<(NND+255)/256, 256, 0, stream>>>(batch, starts, flags);

    // ---- CSR build (once; reused by all 3 layers) ----
    hipMemsetAsync(cnt, 0, NND*sizeof(int), stream);
    hipMemsetAsync(cur, 0, NND*sizeof(int), stream);
    count_kernel<<<(NE+255)/256, 256, 0, stream>>>(ei, cnt, flags);
    scan_kernel<<<1, 1024, 0, stream>>>(cnt, offs);
    fill_kernel<<<(NE+255)/256, 256, 0, stream>>>(ei, offs, cur, csr, flags);

    int gblocks = (NND + 15)/16;

    // ---- layer 1 (input x, K=128) ----
    gemm_l<NF><<<gblocks,256,0,stream>>>(x, W1l, y, flags, 0);
    finalize_kernel<NF><<<gblocks,256,0,stream>>>(x, W1r, b1, y, offs, csr, hA, flags, 0);

    // ---- layer 2 (input hA: f32 ws, K=64) ----
    gemm_l<NH><<<gblocks,256,0,stream>>>(hA, W2l, y, flags, 1);
    finalize_kernel<NH><<<gblocks,256,0,stream>>>(hA, W2r, b2, y, offs, csr, hB, flags, 1);

    // ---- layer 3 (input hB: f32 ws, K=64) ----
    gemm_l<NH><<<gblocks,256,0,stream>>>(hB, W3l, y, flags, 1);
    finalize_kernel<NH><<<gblocks,256,0,stream>>>(hB, W3r, b3, y, offs, csr, hA, flags, 1);

    // ---- head ----
    head_kernel<<<NB,256,0,stream>>>(hA, starts, convw, convb, l1w, l1b, l2w, l2b, out, flags);
}

// Round 4
// 442.731 us; speedup vs baseline: 2.2181x; 1.5615x over previous
//
#include <hip/hip_runtime.h>
#include <hip/hip_bf16.h>
#include <math.h>

#define NND 50000
#define NE 800000
#define NF 128
#define NH 64
#define NB 512
#define KP 30
#define NCLS 10

typedef __hip_bfloat16 bf16;

__device__ __forceinline__ float ldF(const void* p, size_t i, int isbf){
    return isbf ? __bfloat162float(((const bf16*)p)[i]) : ((const float*)p)[i];
}

// ---------------- dtype probe: flags[0]=floats-are-bf16, flags[1]=ints-are-int64 ----
__global__ void probe_kernel(const unsigned int* __restrict__ xw,
                             const int* __restrict__ ew, int* __restrict__ flags){
    __shared__ int cF, cI;
    if (threadIdx.x == 0){ cF = 0; cI = 0; }
    __syncthreads();
    unsigned int w = xw[threadIdx.x];
    int ex = (int)((w >> 7) & 0xFF);
    if (ex >= 100 && ex <= 140) atomicAdd(&cF, 1);
    if (ew[2*threadIdx.x + 1] == 0) atomicAdd(&cI, 1);
    __syncthreads();
    if (threadIdx.x == 0){
        flags[0] = (cF >= 128) ? 1 : 0;
        flags[1] = (cI >= 192) ? 1 : 0;
    }
}

__device__ __forceinline__ int edgeSrc(const int* ei, int e, int i64){
    return i64 ? ei[2*e] : ei[e];
}
__device__ __forceinline__ int edgeDst(const int* ei, int e, int i64){
    return i64 ? ei[2*NE + 2*e] : ei[NE + e];
}

// ---------------- per-graph start offsets (batch sorted) ----------------
__global__ __launch_bounds__(256) void starts_kernel(const int* __restrict__ batch,
                                                     int* __restrict__ starts,
                                                     const int* __restrict__ flags){
    int i = blockIdx.x*256 + threadIdx.x;
    if (i >= NND) return;
    int i64 = flags[1];
    int b  = i64 ? batch[2*i] : batch[i];
    int pb = (i == 0) ? -1 : (i64 ? batch[2*(i-1)] : batch[i-1]);
    for (int g = pb+1; g <= b; ++g) starts[g] = i;
    if (i == NND-1) for (int g = b+1; g <= NB; ++g) starts[g] = NND;
}

// ---------------- CSR build ----------------
__global__ __launch_bounds__(256) void count_kernel(const int* __restrict__ ei,
                                                    int* __restrict__ cnt,
                                                    const int* __restrict__ flags){
    int e = blockIdx.x*256 + threadIdx.x;
    if (e >= NE) return;
    atomicAdd(&cnt[edgeDst(ei, e, flags[1])], 1);
}

// hierarchical exclusive scan of cnt -> offs
__global__ __launch_bounds__(1024) void scan1_kernel(const int* __restrict__ cnt,
                                                     int* __restrict__ offs,
                                                     int* __restrict__ bsum){
    __shared__ int buf[1024];
    int tid = threadIdx.x;
    int i = blockIdx.x*1024 + tid;
    int v = (i < NND) ? cnt[i] : 0;
    buf[tid] = v;
    __syncthreads();
    for (int st = 1; st < 1024; st <<= 1){
        int t = (tid >= st) ? buf[tid-st] : 0;
        __syncthreads();
        buf[tid] += t;
        __syncthreads();
    }
    if (i < NND) offs[i] = buf[tid] - v;      // block-local exclusive
    if (tid == 1023) bsum[blockIdx.x] = buf[1023];
}
__global__ void scan2_kernel(int* __restrict__ bsum, int nb){
    if (threadIdx.x == 0){
        int acc = 0;
        for (int b = 0; b < nb; ++b){ int t = bsum[b]; bsum[b] = acc; acc += t; }
    }
}
__global__ __launch_bounds__(256) void scan3_kernel(int* __restrict__ offs,
                                                    const int* __restrict__ bsum){
    int i = blockIdx.x*256 + threadIdx.x;
    if (i < NND) offs[i] += bsum[i >> 10];
    if (i == 0) offs[NND] = NE;
}

__global__ __launch_bounds__(256) void fill_kernel(const int* __restrict__ ei,
                                                   const int* __restrict__ offs,
                                                   int* __restrict__ cur,
                                                   int* __restrict__ csr,
                                                   const int* __restrict__ flags){
    int e = blockIdx.x*256 + threadIdx.x;
    if (e >= NE) return;
    int i64 = flags[1];
    int d = edgeDst(ei, e, i64);
    int p = atomicAdd(&cur[d], 1);
    csr[offs[d] + p] = edgeSrc(ei, e, i64);
}

// ---------------- dual GEMM: y = h@Wl ; z = h@Wr + b  (weights streamed) ----------
template<int K, typename TW>
__device__ __forceinline__ void dual_loop(const TW* __restrict__ Wl, const TW* __restrict__ Wr,
                                          const float* r0, const float* r1,
                                          const float* r2, const float* r3,
                                          int f, float* ay, float* az){
    #pragma unroll 4
    for (int k = 0; k < K; ++k){
        float wl = (float)Wl[(size_t)k*NH + f];
        float wr = (float)Wr[(size_t)k*NH + f];
        float v0 = r0[k], v1 = r1[k], v2 = r2[k], v3 = r3[k];
        ay[0] += wl*v0; ay[1] += wl*v1; ay[2] += wl*v2; ay[3] += wl*v3;
        az[0] += wr*v0; az[1] += wr*v1; az[2] += wr*v2; az[3] += wr*v3;
    }
}

template<int K>
__global__ __launch_bounds__(256) void dualgemm_kernel(
    const void* __restrict__ in, const void* __restrict__ Wl_,
    const void* __restrict__ Wr_, const void* __restrict__ bias,
    float* __restrict__ y, float* __restrict__ z,
    const int* __restrict__ flags, int inIsF32)
{
    __shared__ float inR[16*K];
    int isbf = inIsF32 ? 0 : flags[0];
    int wbf  = flags[0];
    int tid = threadIdx.x;
    int base = blockIdx.x * 16;
    for (int i = tid; i < 16*K; i += 256){
        int r = i / K, c = i - r*K;
        int node = base + r;
        inR[i] = (node < NND) ? ldF(in, (size_t)node*K + c, isbf) : 0.f;
    }
    __syncthreads();
    int f = tid & 63, ng = tid >> 6;
    float ay[4] = {0,0,0,0}, az[4] = {0,0,0,0};
    const float* r0 = &inR[(ng*4+0)*K];
    const float* r1 = &inR[(ng*4+1)*K];
    const float* r2 = &inR[(ng*4+2)*K];
    const float* r3 = &inR[(ng*4+3)*K];
    if (wbf) dual_loop<K>((const bf16*)Wl_, (const bf16*)Wr_, r0,r1,r2,r3, f, ay, az);
    else     dual_loop<K>((const float*)Wl_,(const float*)Wr_, r0,r1,r2,r3, f, ay, az);
    float bv = ldF(bias, f, wbf);
    #pragma unroll
    for (int j = 0; j < 4; ++j){
        int node = base + ng*4 + j;
        if (node < NND){
            y[(size_t)node*NH + f] = ay[j];
            z[(size_t)node*NH + f] = az[j] + bv;
        }
    }
}

// ---------------- pure gather: out = relu( mean_csr(y) + z ), float4, no LDS ------
__global__ __launch_bounds__(256) void gather_kernel(
    const float4* __restrict__ y4, const int* __restrict__ offs,
    const int* __restrict__ csr, const float* __restrict__ z,
    float* __restrict__ out)
{
    int t = blockIdx.x*256 + threadIdx.x;
    int node = t >> 4;
    int q = t & 15;
    if (node >= NND) return;
    int o0 = offs[node], o1 = offs[node+1];
    float ax=0.f, ayv=0.f, azv=0.f, aw=0.f;
    int e = o0;
    for (; e + 3 < o1; e += 4){
        int s0 = csr[e], s1 = csr[e+1], s2 = csr[e+2], s3 = csr[e+3];
        float4 a = y4[(size_t)s0*16 + q];
        float4 b = y4[(size_t)s1*16 + q];
        float4 c = y4[(size_t)s2*16 + q];
        float4 d = y4[(size_t)s3*16 + q];
        ax  += a.x + b.x + c.x + d.x;
        ayv += a.y + b.y + c.y + d.y;
        azv += a.z + b.z + c.z + d.z;
        aw  += a.w + b.w + c.w + d.w;
    }
    for (; e < o1; ++e){
        float4 a = y4[(size_t)csr[e]*16 + q];
        ax += a.x; ayv += a.y; azv += a.z; aw += a.w;
    }
    float dd = (float)(o1 - o0); dd = dd > 1.f ? dd : 1.f;
    float inv = 1.f / dd;
    size_t base = (size_t)node*NH + q*4;
    float4 zz = *(const float4*)&z[base];
    float4 v;
    v.x = ax *inv + zz.x; v.y = ayv*inv + zz.y;
    v.z = azv*inv + zz.z; v.w = aw *inv + zz.w;
    v.x = v.x > 0.f ? v.x : 0.f;  v.y = v.y > 0.f ? v.y : 0.f;
    v.z = v.z > 0.f ? v.z : 0.f;  v.w = v.w > 0.f ? v.w : 0.f;
    *(float4*)&out[base] = v;
}

// ---------------- fused head: sort-pool topK + conv1d + fc1 + fc2 + log_softmax ----
__global__ __launch_bounds__(256) void head_kernel(
    const float* __restrict__ h3, const int* __restrict__ starts,
    const void* __restrict__ convw, const void* __restrict__ convb,
    const void* __restrict__ lin1w, const void* __restrict__ lin1b,
    const void* __restrict__ lin2w, const void* __restrict__ lin2b,
    float* __restrict__ outp, const int* __restrict__ flags)
{
    __shared__ float vals[2048];
    __shared__ float pooled[KP][NH+1];
    __shared__ float cw[32*321 + 5];     // per-o stride 321 (321%32==1: no bank aliasing)
    __shared__ float cbuf[32*26];
    __shared__ float part[4][NH];
    __shared__ float fbuf[NH];
    __shared__ int   sel[KP];
    __shared__ float logitsS[NCLS];

    int wbf = flags[0];
    int g = blockIdx.x, tid = threadIdx.x;
    int s = starts[g], e = starts[g+1];
    int cnt = e - s; if (cnt > 2048) cnt = 2048; if (cnt < 0) cnt = 0;

    for (int i = tid; i < cnt; i += 256) vals[i] = h3[(size_t)(s+i)*NH + 63];
    __syncthreads();

    if (tid < 64){
        // single-wave top-K selection: no barriers, shfl butterfly
        for (int r = 0; r < KP; ++r){
            float bv = -1e30f; int bi = 0x7fffffff;
            for (int i = tid; i < cnt; i += 64){
                float v = vals[i];
                if (v > bv || (v == bv && i < bi)){ bv = v; bi = i; }
            }
            #pragma unroll
            for (int st = 32; st > 0; st >>= 1){
                float ov = __shfl_xor(bv, st, 64);
                int   oi = __shfl_xor(bi, st, 64);
                if (ov > bv || (ov == bv && oi < bi)){ bv = ov; bi = oi; }
            }
            if (tid == 0){
                if (bv > -1e29f){ sel[r] = bi; vals[bi] = -1e30f; }
                else sel[r] = -1;
            }
        }
    } else {
        // waves 1..3 stage conv weights concurrently
        for (int i = tid - 64; i < 32*NH*5; i += 192){
            int o = i / 320, rem = i - o*320;
            cw[o*321 + rem] = ldF(convw, i, wbf);
        }
    }
    __syncthreads();

    for (int i = tid; i < KP*NH; i += 256){
        int r = i >> 6, f = i & 63;
        int li = sel[r];
        pooled[r][f] = (li >= 0) ? h3[(size_t)(s+li)*NH + f] : 0.f;
    }
    __syncthreads();

    for (int i = tid; i < 32*26; i += 256){
        int o = i / 26, t = i - o*26;
        float a = ldF(convb, o, wbf);
        const float* wo = &cw[o*321];
        for (int ch = 0; ch < NH; ++ch){
            #pragma unroll
            for (int h = 0; h < 5; ++h)
                a += pooled[t+h][ch] * wo[ch*5+h];
        }
        cbuf[o*26+t] = a > 0.f ? a : 0.f;
    }
    __syncthreads();

    {
        int p = tid >> 6, j = tid & 63;
        float a = 0.f;
        int m0 = p*208, m1 = m0+208;
        for (int m = m0; m < m1; ++m)
            a += cbuf[m] * ldF(lin1w, (size_t)m*NH + j, wbf);
        part[p][j] = a;
    }
    __syncthreads();
    if (tid < NH){
        float v = part[0][tid]+part[1][tid]+part[2][tid]+part[3][tid] + ldF(lin1b, tid, wbf);
        fbuf[tid] = v > 0.f ? v : 0.f;
    }
    __syncthreads();

    if (tid < NCLS){
        float a = ldF(lin2b, tid, wbf);
        for (int j = 0; j < NH; ++j) a += fbuf[j] * ldF(lin2w, (size_t)j*NCLS + tid, wbf);
        logitsS[tid] = a;
    }
    __syncthreads();
    if (tid == 0){
        float m = logitsS[0];
        for (int c = 1; c < NCLS; ++c) m = fmaxf(m, logitsS[c]);
        float ssum = 0.f;
        for (int c = 0; c < NCLS; ++c) ssum += expf(logitsS[c]-m);
        float lse = m + logf(ssum);
        for (int c = 0; c < NCLS; ++c)
            outp[(size_t)g*NCLS + c] = logitsS[c] - lse;
    }
}

extern "C" void kernel_launch(void* const* d_in, const int* in_sizes, int n_in,
                              void* d_out, int out_size, void* d_ws, size_t ws_size,
                              hipStream_t stream) {
    const void* x    = d_in[0];
    const int*  ei   = (const int*)d_in[1];
    const int*  batch= (const int*)d_in[2];
    const void *W1l=d_in[3], *b1=d_in[4],  *W1r=d_in[5];
    const void *W2l=d_in[6], *b2=d_in[7],  *W2r=d_in[8];
    const void *W3l=d_in[9], *b3=d_in[10], *W3r=d_in[11];
    const void *convw=d_in[12], *convb=d_in[13];
    const void *l1w=d_in[14], *l1b=d_in[15];
    const void *l2w=d_in[16], *l2b=d_in[17];
    float* out = (float*)d_out;

    float* wsf = (float*)d_ws;
    float* A = wsf;                             // 50000*64 f (y scratch)
    float* Bb = A + (size_t)NND*NH;             // 50000*64 f
    float* C = Bb + (size_t)NND*NH;             // 50000*64 f
    int* starts = (int*)(C + (size_t)NND*NH);   // 513
    int* flags  = starts + 520;                 // 2
    int* cnt    = flags + 8;                    // 50000
    int* offs   = cnt + NND;                    // 50001
    int* cur    = offs + NND + 3;               // 50000
    int* bsum   = cur + NND;                    // 64
    int* csr    = bsum + 64;                    // 800000

    const int NBLK = (NND + 1023)/1024;         // 49

    probe_kernel<<<1, 256, 0, stream>>>((const unsigned int*)x, ei, flags);
    starts_kernel<<<(NND+255)/256, 256, 0, stream>>>(batch, starts, flags);

    // ---- CSR build (once) ----
    hipMemsetAsync(cnt, 0, NND*sizeof(int), stream);
    hipMemsetAsync(cur, 0, NND*sizeof(int), stream);
    count_kernel<<<(NE+255)/256, 256, 0, stream>>>(ei, cnt, flags);
    scan1_kernel<<<NBLK, 1024, 0, stream>>>(cnt, offs, bsum);
    scan2_kernel<<<1, 64, 0, stream>>>(bsum, NBLK);
    scan3_kernel<<<(NND+255)/256, 256, 0, stream>>>(offs, bsum);
    fill_kernel<<<(NE+255)/256, 256, 0, stream>>>(ei, offs, cur, csr, flags);

    int gblocks = (NND + 15)/16;                // 3125
    int ngath   = (NND*16 + 255)/256;           // 3125

    // ---- layer 1: x -> B ----
    dualgemm_kernel<NF><<<gblocks,256,0,stream>>>(x, W1l, W1r, b1, A, Bb, flags, 0);
    gather_kernel<<<ngath,256,0,stream>>>((const float4*)A, offs, csr, Bb, Bb);

    // ---- layer 2: B -> C ----
    dualgemm_kernel<NH><<<gblocks,256,0,stream>>>(Bb, W2l, W2r, b2, A, C, flags, 1);
    gather_kernel<<<ngath,256,0,stream>>>((const float4*)A, offs, csr, C, C);

    // ---- layer 3: C -> B ----
    dualgemm_kernel<NH><<<gblocks,256,0,stream>>>(C, W3l, W3r, b3, A, Bb, flags, 1);
    gather_kernel<<<ngath,256,0,stream>>>((const float4*)A, offs, csr, Bb, Bb);

    // ---- head ----
    head_kernel<<<NB,256,0,stream>>>(Bb, starts, convw, convb, l1w, l1b, l2w, l2b, out, flags);
}

// Round 5
// 412.358 us; speedup vs baseline: 2.3815x; 1.0737x over previous
//
#include <hip/hip_runtime.h>
#include <hip/hip_bf16.h>
#include <math.h>

#define NND 50000
#define NE 800000
#define NF 128
#define NH 64
#define NB 512
#define KP 30
#define NCLS 10

typedef __hip_bfloat16 bf16;

__device__ __forceinline__ float ldF(const void* p, size_t i, int isbf){
    return isbf ? __bfloat162float(((const bf16*)p)[i]) : ((const float*)p)[i];
}

// ---------------- dtype probe: flags[0]=floats-are-bf16, flags[1]=ints-are-int64 ----
__global__ void probe_kernel(const unsigned int* __restrict__ xw,
                             const int* __restrict__ ew, int* __restrict__ flags){
    __shared__ int cF, cI;
    if (threadIdx.x == 0){ cF = 0; cI = 0; }
    __syncthreads();
    unsigned int w = xw[threadIdx.x];
    int ex = (int)((w >> 7) & 0xFF);
    if (ex >= 100 && ex <= 140) atomicAdd(&cF, 1);
    if (ew[2*threadIdx.x + 1] == 0) atomicAdd(&cI, 1);
    __syncthreads();
    if (threadIdx.x == 0){
        flags[0] = (cF >= 128) ? 1 : 0;
        flags[1] = (cI >= 192) ? 1 : 0;
    }
}

__device__ __forceinline__ int edgeSrc(const int* ei, int e, int i64){
    return i64 ? ei[2*e] : ei[e];
}
__device__ __forceinline__ int edgeDst(const int* ei, int e, int i64){
    return i64 ? ei[2*NE + 2*e] : ei[NE + e];
}

// ---------------- per-graph start offsets (batch sorted) ----------------
__global__ __launch_bounds__(256) void starts_kernel(const int* __restrict__ batch,
                                                     int* __restrict__ starts,
                                                     const int* __restrict__ flags){
    int i = blockIdx.x*256 + threadIdx.x;
    if (i >= NND) return;
    int i64 = flags[1];
    int b  = i64 ? batch[2*i] : batch[i];
    int pb = (i == 0) ? -1 : (i64 ? batch[2*(i-1)] : batch[i-1]);
    for (int g = pb+1; g <= b; ++g) starts[g] = i;
    if (i == NND-1) for (int g = b+1; g <= NB; ++g) starts[g] = NND;
}

// ---------------- CSR build ----------------
__global__ __launch_bounds__(256) void count_kernel(const int* __restrict__ ei,
                                                    int* __restrict__ cnt,
                                                    const int* __restrict__ flags){
    int e = blockIdx.x*256 + threadIdx.x;
    if (e >= NE) return;
    atomicAdd(&cnt[edgeDst(ei, e, flags[1])], 1);
}

__global__ __launch_bounds__(1024) void scan1_kernel(const int* __restrict__ cnt,
                                                     int* __restrict__ offs,
                                                     int* __restrict__ bsum){
    __shared__ int buf[1024];
    int tid = threadIdx.x;
    int i = blockIdx.x*1024 + tid;
    int v = (i < NND) ? cnt[i] : 0;
    buf[tid] = v;
    __syncthreads();
    for (int st = 1; st < 1024; st <<= 1){
        int t = (tid >= st) ? buf[tid-st] : 0;
        __syncthreads();
        buf[tid] += t;
        __syncthreads();
    }
    if (i < NND) offs[i] = buf[tid] - v;
    if (tid == 1023) bsum[blockIdx.x] = buf[1023];
}
__global__ void scan2_kernel(int* __restrict__ bsum, int nb){
    if (threadIdx.x == 0){
        int acc = 0;
        for (int b = 0; b < nb; ++b){ int t = bsum[b]; bsum[b] = acc; acc += t; }
    }
}
__global__ __launch_bounds__(256) void scan3_kernel(int* __restrict__ offs,
                                                    const int* __restrict__ bsum){
    int i = blockIdx.x*256 + threadIdx.x;
    if (i < NND) offs[i] += bsum[i >> 10];
    if (i == 0) offs[NND] = NE;
}

__global__ __launch_bounds__(256) void fill_kernel(const int* __restrict__ ei,
                                                   const int* __restrict__ offs,
                                                   int* __restrict__ cur,
                                                   int* __restrict__ csr,
                                                   const int* __restrict__ flags){
    int e = blockIdx.x*256 + threadIdx.x;
    if (e >= NE) return;
    int i64 = flags[1];
    int d = edgeDst(ei, e, i64);
    int p = atomicAdd(&cur[d], 1);
    csr[offs[d] + p] = edgeSrc(ei, e, i64);
}

// ---------------- dual GEMM: y = h@Wl ; z = h@Wr + b ----------------
template<int K, typename TW>
__device__ __forceinline__ void dual_loop(const TW* __restrict__ Wl, const TW* __restrict__ Wr,
                                          const float* r0, const float* r1,
                                          const float* r2, const float* r3,
                                          int f, float* ay, float* az){
    #pragma unroll 4
    for (int k = 0; k < K; ++k){
        float wl = (float)Wl[(size_t)k*NH + f];
        float wr = (float)Wr[(size_t)k*NH + f];
        float v0 = r0[k], v1 = r1[k], v2 = r2[k], v3 = r3[k];
        ay[0] += wl*v0; ay[1] += wl*v1; ay[2] += wl*v2; ay[3] += wl*v3;
        az[0] += wr*v0; az[1] += wr*v1; az[2] += wr*v2; az[3] += wr*v3;
    }
}

template<int K>
__global__ __launch_bounds__(256) void dualgemm_kernel(
    const void* __restrict__ in, const void* __restrict__ Wl_,
    const void* __restrict__ Wr_, const void* __restrict__ bias,
    float* __restrict__ y, float* __restrict__ z,
    const int* __restrict__ flags, int inIsF32)
{
    __shared__ float inR[16*K];
    int isbf = inIsF32 ? 0 : flags[0];
    int wbf  = flags[0];
    int tid = threadIdx.x;
    int base = blockIdx.x * 16;
    for (int i = tid; i < 16*K; i += 256){
        int r = i / K, c = i - r*K;
        int node = base + r;
        inR[i] = (node < NND) ? ldF(in, (size_t)node*K + c, isbf) : 0.f;
    }
    __syncthreads();
    int f = tid & 63, ng = tid >> 6;
    float ay[4] = {0,0,0,0}, az[4] = {0,0,0,0};
    const float* r0 = &inR[(ng*4+0)*K];
    const float* r1 = &inR[(ng*4+1)*K];
    const float* r2 = &inR[(ng*4+2)*K];
    const float* r3 = &inR[(ng*4+3)*K];
    if (wbf) dual_loop<K>((const bf16*)Wl_, (const bf16*)Wr_, r0,r1,r2,r3, f, ay, az);
    else     dual_loop<K>((const float*)Wl_,(const float*)Wr_, r0,r1,r2,r3, f, ay, az);
    float bv = ldF(bias, f, wbf);
    #pragma unroll
    for (int j = 0; j < 4; ++j){
        int node = base + ng*4 + j;
        if (node < NND){
            y[(size_t)node*NH + f] = ay[j];
            z[(size_t)node*NH + f] = az[j] + bv;
        }
    }
}

// ---------------- pure gather: out = relu( mean_csr(y) + z ), float4 ------
__global__ __launch_bounds__(256) void gather_kernel(
    const float4* __restrict__ y4, const int* __restrict__ offs,
    const int* __restrict__ csr, const float* __restrict__ z,
    float* __restrict__ out)
{
    int t = blockIdx.x*256 + threadIdx.x;
    int node = t >> 4;
    int q = t & 15;
    if (node >= NND) return;
    int o0 = offs[node], o1 = offs[node+1];
    float ax=0.f, ayv=0.f, azv=0.f, aw=0.f;
    int e = o0;
    for (; e + 3 < o1; e += 4){
        int s0 = csr[e], s1 = csr[e+1], s2 = csr[e+2], s3 = csr[e+3];
        float4 a = y4[(size_t)s0*16 + q];
        float4 b = y4[(size_t)s1*16 + q];
        float4 c = y4[(size_t)s2*16 + q];
        float4 d = y4[(size_t)s3*16 + q];
        ax  += a.x + b.x + c.x + d.x;
        ayv += a.y + b.y + c.y + d.y;
        azv += a.z + b.z + c.z + d.z;
        aw  += a.w + b.w + c.w + d.w;
    }
    for (; e < o1; ++e){
        float4 a = y4[(size_t)csr[e]*16 + q];
        ax += a.x; ayv += a.y; azv += a.z; aw += a.w;
    }
    float dd = (float)(o1 - o0); dd = dd > 1.f ? dd : 1.f;
    float inv = 1.f / dd;
    size_t base = (size_t)node*NH + q*4;
    float4 zz = *(const float4*)&z[base];
    float4 v;
    v.x = ax *inv + zz.x; v.y = ayv*inv + zz.y;
    v.z = azv*inv + zz.z; v.w = aw *inv + zz.w;
    v.x = v.x > 0.f ? v.x : 0.f;  v.y = v.y > 0.f ? v.y : 0.f;
    v.z = v.z > 0.f ? v.z : 0.f;  v.w = v.w > 0.f ? v.w : 0.f;
    *(float4*)&out[base] = v;
}

// ---------------- weight preconvert for head (fp32, conv transposed) ----------
__global__ __launch_bounds__(256) void prep_kernel(
    const void* __restrict__ convw, const void* __restrict__ convb,
    const void* __restrict__ l1w, const void* __restrict__ l1b,
    const void* __restrict__ l2w, const void* __restrict__ l2b,
    float* __restrict__ wT, float* __restrict__ cbf,
    float* __restrict__ l1wf, float* __restrict__ l1bf,
    float* __restrict__ l2wf, float* __restrict__ l2bf,
    const int* __restrict__ flags)
{
    int wbf = flags[0];
    int i = blockIdx.x*256 + threadIdx.x;
    if (i < 10240){
        int o = i / 320, rem = i - o*320, ch = rem/5, h = rem - ch*5;
        wT[ch*160 + h*32 + o] = ldF(convw, i, wbf);   // wT[ch][h][o]
    }
    if (i < 53248) l1wf[i] = ldF(l1w, i, wbf);
    if (i < 640)   l2wf[i] = ldF(l2w, i, wbf);
    if (i < 64)    l1bf[i] = ldF(l1b, i, wbf);
    if (i < 32)    cbf[i]  = ldF(convb, i, wbf);
    if (i < 10)    l2bf[i] = ldF(l2b, i, wbf);
}

// ------------- selection: per-graph top-30 by ch63, write pooledT[g][64][32] -------
__global__ __launch_bounds__(64) void select_kernel(
    const float* __restrict__ h3, const int* __restrict__ starts,
    float* __restrict__ pooledT)
{
    int g = blockIdx.x, lane = threadIdx.x;
    int s = starts[g], e = starts[g+1];
    int cnt = e - s; if (cnt > 256) cnt = 256; if (cnt < 0) cnt = 0;
    float k0 = (lane       < cnt) ? h3[(size_t)(s+lane      )*NH + 63] : -1e30f;
    float k1 = (lane + 64  < cnt) ? h3[(size_t)(s+lane +  64)*NH + 63] : -1e30f;
    float k2 = (lane + 128 < cnt) ? h3[(size_t)(s+lane + 128)*NH + 63] : -1e30f;
    float k3 = (lane + 192 < cnt) ? h3[(size_t)(s+lane + 192)*NH + 63] : -1e30f;
    float pr[32];
    pr[30] = 0.f; pr[31] = 0.f;
    #pragma unroll
    for (int r = 0; r < KP; ++r){
        float bv = k0; int bi = lane;
        if (k1 > bv){ bv = k1; bi = lane + 64;  }
        if (k2 > bv){ bv = k2; bi = lane + 128; }
        if (k3 > bv){ bv = k3; bi = lane + 192; }
        #pragma unroll
        for (int st = 32; st > 0; st >>= 1){
            float ov = __shfl_xor(bv, st, 64);
            int   oi = __shfl_xor(bi, st, 64);
            if (ov > bv || (ov == bv && oi < bi)){ bv = ov; bi = oi; }
        }
        float v = 0.f;
        if (bv > -1e29f){
            v = h3[(size_t)(s+bi)*NH + lane];       // coalesced row read
            if      (bi == lane      ) k0 = -1e30f;
            else if (bi == lane + 64 ) k1 = -1e30f;
            else if (bi == lane + 128) k2 = -1e30f;
            else if (bi == lane + 192) k3 = -1e30f;
        }
        pr[r] = v;
    }
    float4* dst = (float4*)&pooledT[((size_t)g*64 + lane)*32];
    #pragma unroll
    for (int q = 0; q < 8; ++q)
        dst[q] = make_float4(pr[4*q], pr[4*q+1], pr[4*q+2], pr[4*q+3]);
}

// ------------- head2: conv (register-blocked) + fc1 + fc2 + log_softmax -------
__global__ __launch_bounds__(256) void head2_kernel(
    const float* __restrict__ pooledT, const float* __restrict__ wT,
    const float* __restrict__ cbf, const float* __restrict__ l1wf,
    const float* __restrict__ l1bf, const float* __restrict__ l2wf,
    const float* __restrict__ l2bf, float* __restrict__ outp)
{
    __shared__ float pT[64*32];
    __shared__ float part[8*832];
    __shared__ float cbuf[832];
    __shared__ float fbuf[NH];
    __shared__ float logitsS[NCLS];
    int g = blockIdx.x, tid = threadIdx.x;

    const float4* src4 = (const float4*)&pooledT[(size_t)g*2048];
    float4* pT4 = (float4*)pT;
    for (int i = tid; i < 512; i += 256) pT4[i] = src4[i];
    __syncthreads();

    int o = tid & 31, chg = tid >> 5;
    float acc[26];
    #pragma unroll
    for (int t = 0; t < 26; ++t) acc[t] = 0.f;
    for (int c8 = 0; c8 < 8; ++c8){
        int ch = chg*8 + c8;
        const float4* prow = (const float4*)&pT[ch*32];
        float p[32];
        #pragma unroll
        for (int q = 0; q < 8; ++q){
            float4 v = prow[q];
            p[4*q]=v.x; p[4*q+1]=v.y; p[4*q+2]=v.z; p[4*q+3]=v.w;
        }
        const float* wrow = &wT[ch*160 + o];
        #pragma unroll
        for (int h = 0; h < 5; ++h){
            float wv = wrow[h*32];                  // coalesced across o-lanes
            #pragma unroll
            for (int t = 0; t < 26; ++t) acc[t] += p[t+h]*wv;
        }
    }
    #pragma unroll
    for (int t = 0; t < 26; ++t) part[chg*832 + o*26 + t] = acc[t];
    __syncthreads();

    for (int i = tid; i < 832; i += 256){
        int oo = i / 26;
        float a = cbf[oo];
        #pragma unroll
        for (int cg = 0; cg < 8; ++cg) a += part[cg*832 + i];
        cbuf[i] = a > 0.f ? a : 0.f;
    }
    __syncthreads();

    {   // fc1: 832 -> 64, 4 partial groups
        int p = tid >> 6, j = tid & 63;
        float a = 0.f;
        int m0 = p*208;
        #pragma unroll 4
        for (int m = m0; m < m0 + 208; ++m)
            a += cbuf[m] * l1wf[(size_t)m*NH + j];
        part[p*NH + j] = a;
    }
    __syncthreads();
    if (tid < NH){
        float v = part[tid] + part[NH+tid] + part[2*NH+tid] + part[3*NH+tid] + l1bf[tid];
        fbuf[tid] = v > 0.f ? v : 0.f;
    }
    __syncthreads();
    if (tid < NCLS){
        float a = l2bf[tid];
        #pragma unroll
        for (int j = 0; j < NH; ++j) a += fbuf[j] * l2wf[j*NCLS + tid];
        logitsS[tid] = a;
    }
    __syncthreads();
    if (tid == 0){
        float m = logitsS[0];
        for (int c = 1; c < NCLS; ++c) m = fmaxf(m, logitsS[c]);
        float ssum = 0.f;
        for (int c = 0; c < NCLS; ++c) ssum += expf(logitsS[c]-m);
        float lse = m + logf(ssum);
        for (int c = 0; c < NCLS; ++c)
            outp[(size_t)g*NCLS + c] = logitsS[c] - lse;
    }
}

extern "C" void kernel_launch(void* const* d_in, const int* in_sizes, int n_in,
                              void* d_out, int out_size, void* d_ws, size_t ws_size,
                              hipStream_t stream) {
    const void* x    = d_in[0];
    const int*  ei   = (const int*)d_in[1];
    const int*  batch= (const int*)d_in[2];
    const void *W1l=d_in[3], *b1=d_in[4],  *W1r=d_in[5];
    const void *W2l=d_in[6], *b2=d_in[7],  *W2r=d_in[8];
    const void *W3l=d_in[9], *b3=d_in[10], *W3r=d_in[11];
    const void *convw=d_in[12], *convb=d_in[13];
    const void *l1w=d_in[14], *l1b=d_in[15];
    const void *l2w=d_in[16], *l2b=d_in[17];
    float* out = (float*)d_out;

    float* wsf = (float*)d_ws;
    float* A  = wsf;                             // 50000*64
    float* Bb = A  + (size_t)NND*NH;             // 50000*64
    float* C  = Bb + (size_t)NND*NH;             // 50000*64
    float* pooledT = C + (size_t)NND*NH;         // 512*64*32 = 1,048,576
    float* wT   = pooledT + (size_t)NB*64*32;    // 10240
    float* cbf  = wT + 10240;                    // 32
    float* l1wf = cbf + 32;                      // 53248
    float* l1bf = l1wf + 53248;                  // 64
    float* l2wf = l1bf + 64;                     // 640
    float* l2bf = l2wf + 640;                    // 10 (+pad)
    int* starts = (int*)(l2bf + 16);             // 513
    int* flags  = starts + 520;                  // 2
    int* cnt    = flags + 8;                     // 50000
    int* offs   = cnt + NND;                     // 50001
    int* cur    = offs + NND + 3;                // 50000
    int* bsum   = cur + NND;                     // 64
    int* csr    = bsum + 64;                     // 800000

    const int NBLK = (NND + 1023)/1024;          // 49

    probe_kernel<<<1, 256, 0, stream>>>((const unsigned int*)x, ei, flags);
    starts_kernel<<<(NND+255)/256, 256, 0, stream>>>(batch, starts, flags);
    prep_kernel<<<(53248+255)/256, 256, 0, stream>>>(convw, convb, l1w, l1b, l2w, l2b,
                                                     wT, cbf, l1wf, l1bf, l2wf, l2bf, flags);

    // ---- CSR build (once) ----
    hipMemsetAsync(cnt, 0, NND*sizeof(int), stream);
    hipMemsetAsync(cur, 0, NND*sizeof(int), stream);
    count_kernel<<<(NE+255)/256, 256, 0, stream>>>(ei, cnt, flags);
    scan1_kernel<<<NBLK, 1024, 0, stream>>>(cnt, offs, bsum);
    scan2_kernel<<<1, 64, 0, stream>>>(bsum, NBLK);
    scan3_kernel<<<(NND+255)/256, 256, 0, stream>>>(offs, bsum);
    fill_kernel<<<(NE+255)/256, 256, 0, stream>>>(ei, offs, cur, csr, flags);

    int gblocks = (NND + 15)/16;                 // 3125
    int ngath   = (NND*16 + 255)/256;            // 3125

    // ---- layer 1: x -> B ----
    dualgemm_kernel<NF><<<gblocks,256,0,stream>>>(x, W1l, W1r, b1, A, Bb, flags, 0);
    gather_kernel<<<ngath,256,0,stream>>>((const float4*)A, offs, csr, Bb, Bb);

    // ---- layer 2: B -> C ----
    dualgemm_kernel<NH><<<gblocks,256,0,stream>>>(Bb, W2l, W2r, b2, A, C, flags, 1);
    gather_kernel<<<ngath,256,0,stream>>>((const float4*)A, offs, csr, C, C);

    // ---- layer 3: C -> B ----
    dualgemm_kernel<NH><<<gblocks,256,0,stream>>>(C, W3l, W3r, b3, A, Bb, flags, 1);
    gather_kernel<<<ngath,256,0,stream>>>((const float4*)A, offs, csr, Bb, Bb);

    // ---- head: selection + dense tail ----
    select_kernel<<<NB,64,0,stream>>>(Bb, starts, pooledT);
    head2_kernel<<<NB,256,0,stream>>>(pooledT, wT, cbf, l1wf, l1bf, l2wf, l2bf, out);
}